// Round 7
// baseline (746.834 us; speedup 1.0000x reference)
//
#include <hip/hip_runtime.h>

// ---------------- constants ----------------
// B=8, C=32, CO=32, NIN=16, NOUT=10, D1=D2=512, NRC=1344
// outputs (fp32, concatenated): zw0[8,32,512,16] zw1[8,32,512,512] zw2[8,32,10,512]
//                               u0[8,32,512] u1[8,32,512] u2[8,32,10]
#define OUT_ZW1 2097152u
#define OUT_ZW2 69206016u
#define OUT_U0  70516736u
#define OUT_U1  70647808u
#define OUT_U2  70778880u

// workspace layout (floats) — no atomics, every cell is written before read
#define WS_RM1P  0u        // [4][8*32][512] raw col-sum partials of w1
#define WS_CM1   524288u   // [8*32][512]
#define WS_CM0   655360u
#define WS_RM2   786432u
#define WS_RCW1  917504u   // [4][256] w1 block-sum partials
#define WS_RC    918528u   // [8][1344] (entries 32..63 are written by STAGE_RC)
#define WS_RTERM 929280u
#define WS_CTERM 1060352u
#define WS_W0T   1191424u  // [8][512][512]

static __device__ __forceinline__ float wave_reduce(float v) {
#pragma unroll
  for (int off = 32; off > 0; off >>= 1) v += __shfl_down(v, off);
  return v;
}

// ---- K1: small stats [0,256) | w1 stats [256,1280) | w0 transpose [1280,1536) ----
__global__ __launch_bounds__(256) void ksetup(
    const float* __restrict__ w0, const float* __restrict__ w2,
    const float* __restrict__ b0, const float* __restrict__ b1,
    const float* __restrict__ b2, const float* __restrict__ w1,
    float* __restrict__ ws) {
  __shared__ float sred[16];
  __shared__ float stot;
  __shared__ float rpart[512];
  __shared__ float swsum[4];
  int tid = threadIdx.x, lane = tid & 63;
  int bx = blockIdx.x;

  if (bx < 256) {
    int bc = bx;
    int b = bc >> 5, c = bc & 31;
    float* rcb = ws + WS_RC + b * 1344;
    float* cm0 = ws + WS_CM0;
    float* rm2 = ws + WS_RM2;

    if (tid < 16) sred[tid] = 0.f;
    if (tid == 0) stot = 0.f;
    __syncthreads();
    {
      float rm0p[16];
#pragma unroll
      for (int k = 0; k < 16; ++k) rm0p[k] = 0.f;
      float tot = 0.f;
      for (int d = tid; d < 512; d += 256) {
        const float4* p = (const float4*)(w0 + ((size_t)bc * 512 + d) * 16);
        float s = 0.f;
#pragma unroll
        for (int q = 0; q < 4; ++q) {
          float4 v = p[q];
          s += v.x + v.y + v.z + v.w;
          rm0p[q * 4 + 0] += v.x; rm0p[q * 4 + 1] += v.y;
          rm0p[q * 4 + 2] += v.z; rm0p[q * 4 + 3] += v.w;
        }
        cm0[(size_t)bc * 512 + d] = s * (1.f / 16.f);
        tot += s;
      }
#pragma unroll
      for (int k = 0; k < 16; ++k) {
        float r = wave_reduce(rm0p[k]);
        if (lane == 0) atomicAdd(&sred[k], r);  // LDS atomic (intra-block only)
      }
      float rt = wave_reduce(tot);
      if (lane == 0) atomicAdd(&stot, rt);
    }
    __syncthreads();
    if (tid < 16) rcb[192 + c * 16 + tid] = sred[tid] * (1.f / 512.f);
    if (tid == 0) rcb[c] = stot * (1.f / 8192.f);
    __syncthreads();

    if (tid < 10) sred[tid] = 0.f;
    if (tid == 0) stot = 0.f;
    __syncthreads();
    {
      float cm2p[10];
#pragma unroll
      for (int k = 0; k < 10; ++k) cm2p[k] = 0.f;
      float tot = 0.f;
      for (int d = tid; d < 512; d += 256) {
        float s = 0.f;
#pragma unroll
        for (int k = 0; k < 10; ++k) {
          float v = w2[((size_t)bc * 10 + k) * 512 + d];
          s += v; cm2p[k] += v;
        }
        rm2[(size_t)bc * 512 + d] = s * 0.1f;
        tot += s;
      }
#pragma unroll
      for (int k = 0; k < 10; ++k) {
        float r = wave_reduce(cm2p[k]);
        if (lane == 0) atomicAdd(&sred[k], r);
      }
      float rt = wave_reduce(tot);
      if (lane == 0) atomicAdd(&stot, rt);
    }
    __syncthreads();
    if (tid < 10) rcb[704 + c * 10 + tid] = sred[tid] * (1.f / 512.f);
    if (tid == 0) rcb[64 + c] = stot * (1.f / 5120.f);
    __syncthreads();

    if (tid < 2) sred[tid] = 0.f;
    __syncthreads();
    {
      float t0 = 0.f, t1 = 0.f;
      for (int d = tid; d < 512; d += 256) {
        t0 += b0[(size_t)bc * 512 + d];
        t1 += b1[(size_t)bc * 512 + d];
      }
      t0 = wave_reduce(t0); t1 = wave_reduce(t1);
      if (lane == 0) { atomicAdd(&sred[0], t0); atomicAdd(&sred[1], t1); }
    }
    __syncthreads();
    if (tid == 0) {
      rcb[96 + c] = sred[0] * (1.f / 512.f);
      rcb[128 + c] = sred[1] * (1.f / 512.f);
    }

    float vb2 = 0.f;
    if (tid < 10) {
      vb2 = b2[bc * 10 + tid];
      rcb[1024 + c * 10 + tid] = vb2;
    }
    if (tid < 64) {
      float s = wave_reduce(vb2);
      if (tid == 0) rcb[160 + c] = s * 0.1f;
    }
  } else if (bx < 1280) {
    // ---- w1 stats: direct partial stores, no global atomics ----
    int idx = bx - 256;
    int bc = idx >> 2, hc = idx & 3;
    int wid = tid >> 6;
    const float* base = w1 + (size_t)bc * 262144 + (size_t)hc * 65536;
    float col0 = 0.f, col1 = 0.f;
    for (int hl = 0; hl < 128; ++hl) {
      float2 x = *(const float2*)(base + hl * 512 + 2 * tid);
      col0 += x.x; col1 += x.y;
      float r = wave_reduce(x.x + x.y);
      if (lane == 0) rpart[hl * 4 + wid] = r;
    }
    __syncthreads();
    if (tid < 128) {
      float s = rpart[tid * 4] + rpart[tid * 4 + 1] + rpart[tid * 4 + 2] + rpart[tid * 4 + 3];
      ws[WS_CM1 + (size_t)bc * 512 + hc * 128 + tid] = s * (1.f / 512.f);
    }
    ws[WS_RM1P + (size_t)hc * 131072 + (size_t)bc * 512 + 2 * tid] = col0;
    ws[WS_RM1P + (size_t)hc * 131072 + (size_t)bc * 512 + 2 * tid + 1] = col1;
    float bt = wave_reduce(col0 + col1);
    if (lane == 0) swsum[wid] = bt;
    __syncthreads();
    if (tid == 0)
      ws[WS_RCW1 + hc * 256 + bc] = swsum[0] + swsum[1] + swsum[2] + swsum[3];
  } else {
    // ---- w0 -> w0T : contiguous 64B reads per thread, coalesced stores per k ----
    int bc = bx - 1280;
    int b = bc >> 5, c = bc & 31;
    for (int dd = 0; dd < 2; ++dd) {
      int d = tid + dd * 256;
      const float4* src = (const float4*)(w0 + ((size_t)bc * 512 + d) * 16);
      float4 v0 = src[0], v1 = src[1], v2 = src[2], v3 = src[3];
      float vals[16] = {v0.x, v0.y, v0.z, v0.w, v1.x, v1.y, v1.z, v1.w,
                        v2.x, v2.y, v2.z, v2.w, v3.x, v3.y, v3.z, v3.w};
#pragma unroll
      for (int k = 0; k < 16; ++k)
        ws[WS_W0T + ((size_t)(b * 512 + c * 16 + k)) * 512 + d] = vals[k];
    }
  }
}

// ---- K2: rterm [0,64) | cterm+u1 [64,192) | z0/u0 [192,1280) | zf [1280,1920) | u2 [1920,1928)
// LDS: wlds 4864 + rcs 1344 + tv 16 = 6224 floats ≈ 24.9 KB -> 6 blocks/CU
__global__ __launch_bounds__(256) void kbig(
    float* __restrict__ ws, float* __restrict__ out,
    const float* __restrict__ b0, const float* __restrict__ b1,
    const float* __restrict__ w2,
    const float* __restrict__ W_l1_r, const float* __restrict__ B_l1_r,
    const float* __restrict__ W_l1_c, const float* __restrict__ B_l1_c,
    const float* __restrict__ B_l1,
    const float* __restrict__ W_bias1, const float* __restrict__ B_bias1,
    const float* __restrict__ W_l1_rc, const float* __restrict__ B_l1_rc,
    const float* __restrict__ W_bias1_rc, const float* __restrict__ B_bias1_rc,
    const float* __restrict__ W_w0_rpt, const float* __restrict__ B_w0_rpt,
    const float* __restrict__ W_b0, const float* __restrict__ B_b0,
    const float* __restrict__ W_w0_rc, const float* __restrict__ B_w0_rc,
    const float* __restrict__ W_b0_rc, const float* __restrict__ B_b0_rc,
    const float* __restrict__ W_fin_cpt, const float* __restrict__ B_fin_cpt,
    const float* __restrict__ W_fin_rc, const float* __restrict__ B_fin_rc,
    const float* __restrict__ W_bfin_rc, const float* __restrict__ B_bfin_rc) {
  __shared__ float wlds[4864];
  __shared__ float rcs[1344];
  __shared__ float tv[16];
  int bid = blockIdx.x, tid = threadIdx.x;
  const float* p0 = ws + WS_RM1P;
  const float* p1 = ws + WS_RM1P + 131072;
  const float* p2 = ws + WS_RM1P + 262144;
  const float* p3 = ws + WS_RM1P + 393216;
  const float* cm0 = ws + WS_CM0;
  const float* cm1 = ws + WS_CM1;
  const float* rm2 = ws + WS_RM2;
  const float* w0T = ws + WS_W0T;

#define STAGE_RC(b_)                                                              \
  do {                                                                            \
    for (int j = tid; j < 1344; j += 256)                                         \
      if (j < 32 || j >= 64) rcs[j] = ws[WS_RC + (b_) * 1344 + j];                \
    if (tid < 32)                                                                 \
      rcs[32 + tid] = (ws[WS_RCW1 + 0 * 256 + (b_) * 32 + tid] +                  \
                       ws[WS_RCW1 + 1 * 256 + (b_) * 32 + tid] +                  \
                       ws[WS_RCW1 + 2 * 256 + (b_) * 32 + tid] +                  \
                       ws[WS_RCW1 + 3 * 256 + (b_) * 32 + tid]) *                 \
                      (1.f / 262144.f);                                           \
  } while (0)

  if (bid < 64) {
    // ======== rterm: 8 outputs/thread, no rc term ========
    int x = bid & 1, oy = (bid >> 1) & 3, b = bid >> 3;
    int p = x * 256 + tid;
    int o0 = oy * 8;
    for (int idx = tid; idx < 608 * 8; idx += 256) {
      int i = idx >> 3, oo = idx & 7;
      wlds[idx] = W_l1_r[(size_t)(o0 + oo) * 608 + i];
    }
    __syncthreads();
    float acc[8] = {0, 0, 0, 0, 0, 0, 0, 0};
#pragma unroll 4
    for (int i = 0; i < 32; ++i) {
      size_t off = ((size_t)b * 32 + i) * 512 + p;
      float xv = (p0[off] + p1[off] + p2[off] + p3[off]) * (1.f / 512.f);
      float4 wa = *(const float4*)&wlds[i * 8];
      float4 wb = *(const float4*)&wlds[i * 8 + 4];
      acc[0] += wa.x * xv; acc[1] += wa.y * xv; acc[2] += wa.z * xv; acc[3] += wa.w * xv;
      acc[4] += wb.x * xv; acc[5] += wb.y * xv; acc[6] += wb.z * xv; acc[7] += wb.w * xv;
    }
#pragma unroll 4
    for (int i = 0; i < 32; ++i) {
      float xv = cm0[((size_t)b * 32 + i) * 512 + p];
      float4 wa = *(const float4*)&wlds[(32 + i) * 8];
      float4 wb = *(const float4*)&wlds[(32 + i) * 8 + 4];
      acc[0] += wa.x * xv; acc[1] += wa.y * xv; acc[2] += wa.z * xv; acc[3] += wa.w * xv;
      acc[4] += wb.x * xv; acc[5] += wb.y * xv; acc[6] += wb.z * xv; acc[7] += wb.w * xv;
    }
#pragma unroll 4
    for (int i = 0; i < 32; ++i) {
      float xv = b0[((size_t)b * 32 + i) * 512 + p];
      float4 wa = *(const float4*)&wlds[(64 + i) * 8];
      float4 wb = *(const float4*)&wlds[(64 + i) * 8 + 4];
      acc[0] += wa.x * xv; acc[1] += wa.y * xv; acc[2] += wa.z * xv; acc[3] += wa.w * xv;
      acc[4] += wb.x * xv; acc[5] += wb.y * xv; acc[6] += wb.z * xv; acc[7] += wb.w * xv;
    }
    const float* xp = w0T + (size_t)b * 512 * 512 + p;
#pragma unroll 4
    for (int i = 0; i < 512; ++i) {
      float xv = xp[(size_t)i * 512];
      float4 wa = *(const float4*)&wlds[(96 + i) * 8];
      float4 wb = *(const float4*)&wlds[(96 + i) * 8 + 4];
      acc[0] += wa.x * xv; acc[1] += wa.y * xv; acc[2] += wa.z * xv; acc[3] += wa.w * xv;
      acc[4] += wb.x * xv; acc[5] += wb.y * xv; acc[6] += wb.z * xv; acc[7] += wb.w * xv;
    }
#pragma unroll
    for (int oo = 0; oo < 8; ++oo) {
      int o = o0 + oo;
      ws[WS_RTERM + ((size_t)b * 32 + o) * 512 + p] = acc[oo] + B_l1_r[o];
    }
  } else if (bid < 192) {
    // ======== cterm + u1: 4 outputs/thread (keeps LDS small) ========
    int t = bid - 64;
    int x = t & 1, oq = (t >> 1) & 7, b = t >> 4;
    int p = x * 256 + tid;
    int o0 = oq * 4;
    for (int idx = tid; idx < 416 * 4; idx += 256) {
      int i = idx >> 2, oo = idx & 3;
      wlds[idx] = W_l1_c[(size_t)(o0 + oo) * 416 + i];
      wlds[1664 + idx] = W_bias1[(size_t)(o0 + oo) * 416 + i];
    }
    STAGE_RC(b);
    __syncthreads();
    {
      int g = tid >> 5, l = tid & 31;
      const float* wr = (g < 4) ? (W_l1_rc + (size_t)(o0 + g) * 1344)
                                : (W_bias1_rc + (size_t)(o0 + g - 4) * 1344);
      float a = 0.f;
      for (int j = l; j < 1344; j += 32) a += wr[j] * rcs[j];
      a += __shfl_xor(a, 16); a += __shfl_xor(a, 8); a += __shfl_xor(a, 4);
      a += __shfl_xor(a, 2); a += __shfl_xor(a, 1);
      if (l == 0) tv[g] = a + ((g < 4) ? B_l1_rc[o0 + g] : B_bias1_rc[o0 + g - 4]);
    }
    __syncthreads();
    float ac[4] = {0, 0, 0, 0};
    float au[4] = {0, 0, 0, 0};
#pragma unroll 4
    for (int i = 0; i < 32; ++i) {
      float xv = cm1[((size_t)b * 32 + i) * 512 + p];
      float4 wa = *(const float4*)&wlds[i * 4];
      float4 va = *(const float4*)&wlds[1664 + i * 4];
      ac[0] += wa.x * xv; ac[1] += wa.y * xv; ac[2] += wa.z * xv; ac[3] += wa.w * xv;
      au[0] += va.x * xv; au[1] += va.y * xv; au[2] += va.z * xv; au[3] += va.w * xv;
    }
#pragma unroll 4
    for (int i = 0; i < 32; ++i) {
      float xv = b1[((size_t)b * 32 + i) * 512 + p];
      float4 wa = *(const float4*)&wlds[(32 + i) * 4];
      float4 va = *(const float4*)&wlds[1664 + (32 + i) * 4];
      ac[0] += wa.x * xv; ac[1] += wa.y * xv; ac[2] += wa.z * xv; ac[3] += wa.w * xv;
      au[0] += va.x * xv; au[1] += va.y * xv; au[2] += va.z * xv; au[3] += va.w * xv;
    }
#pragma unroll 4
    for (int i = 0; i < 32; ++i) {
      float xv = rm2[((size_t)b * 32 + i) * 512 + p];
      float4 wa = *(const float4*)&wlds[(64 + i) * 4];
      float4 va = *(const float4*)&wlds[1664 + (64 + i) * 4];
      ac[0] += wa.x * xv; ac[1] += wa.y * xv; ac[2] += wa.z * xv; ac[3] += wa.w * xv;
      au[0] += va.x * xv; au[1] += va.y * xv; au[2] += va.z * xv; au[3] += va.w * xv;
    }
    const float* xp = w2 + (size_t)b * 320 * 512 + p;
#pragma unroll 4
    for (int i = 0; i < 320; ++i) {
      float xv = xp[(size_t)i * 512];
      float4 wa = *(const float4*)&wlds[(96 + i) * 4];
      float4 va = *(const float4*)&wlds[1664 + (96 + i) * 4];
      ac[0] += wa.x * xv; ac[1] += wa.y * xv; ac[2] += wa.z * xv; ac[3] += wa.w * xv;
      au[0] += va.x * xv; au[1] += va.y * xv; au[2] += va.z * xv; au[3] += va.w * xv;
    }
#pragma unroll
    for (int oo = 0; oo < 4; ++oo) {
      int o = o0 + oo;
      ws[WS_CTERM + ((size_t)b * 32 + o) * 512 + p] = ac[oo] + B_l1_c[o] + B_l1[o] + tv[oo];
      out[OUT_U1 + ((size_t)b * 32 + o) * 512 + p] = au[oo] + B_bias1[o] + tv[4 + oo];
    }
  } else if (bid < 1280) {
    // ======== z0 / u0 ========
    int t = bid - 192;
    int x = t & 1, rest = t >> 1;
    int oc = rest % 68, b = rest / 68;
    bool isZ = oc < 64;
    int o0 = isZ ? oc * 8 : (oc - 64) * 8;
    const float* Wsrc = isZ ? W_w0_rpt : W_b0;
    const float* Wrc = isZ ? W_w0_rc : W_b0_rc;
    const float* Brc = isZ ? B_w0_rc : B_b0_rc;
    for (int idx = tid; idx < 576 * 8; idx += 256) {
      int i = idx >> 3, oo = idx & 7;
      wlds[idx] = Wsrc[(size_t)(o0 + oo) * 576 + i];
    }
    STAGE_RC(b);
    __syncthreads();
    {
      int g = tid >> 5, l = tid & 31;
      const float* wr = Wrc + (size_t)(o0 + g) * 1344;
      float a = 0.f;
      for (int j = l; j < 1344; j += 32) a += wr[j] * rcs[j];
      a += __shfl_xor(a, 16); a += __shfl_xor(a, 8); a += __shfl_xor(a, 4);
      a += __shfl_xor(a, 2); a += __shfl_xor(a, 1);
      if (l == 0) tv[g] = a + Brc[o0 + g];
    }
    __syncthreads();
    int d = x * 256 + tid;
    float acc[8] = {0, 0, 0, 0, 0, 0, 0, 0};
    const float* xp = w0T + (size_t)b * 512 * 512 + d;
#pragma unroll 4
    for (int i = 0; i < 512; ++i) {
      float xv = xp[(size_t)i * 512];
      float4 wa = *(const float4*)&wlds[i * 8];
      float4 wb = *(const float4*)&wlds[i * 8 + 4];
      acc[0] += wa.x * xv; acc[1] += wa.y * xv; acc[2] += wa.z * xv; acc[3] += wa.w * xv;
      acc[4] += wb.x * xv; acc[5] += wb.y * xv; acc[6] += wb.z * xv; acc[7] += wb.w * xv;
    }
#pragma unroll 4
    for (int i = 0; i < 32; ++i) {
      size_t off = ((size_t)b * 32 + i) * 512 + d;
      float xv = (p0[off] + p1[off] + p2[off] + p3[off]) * (1.f / 512.f);
      float4 wa = *(const float4*)&wlds[(512 + i) * 8];
      float4 wb = *(const float4*)&wlds[(512 + i) * 8 + 4];
      acc[0] += wa.x * xv; acc[1] += wa.y * xv; acc[2] += wa.z * xv; acc[3] += wa.w * xv;
      acc[4] += wb.x * xv; acc[5] += wb.y * xv; acc[6] += wb.z * xv; acc[7] += wb.w * xv;
    }
#pragma unroll 4
    for (int i = 0; i < 32; ++i) {
      float xv = b0[((size_t)b * 32 + i) * 512 + d];
      float4 wa = *(const float4*)&wlds[(544 + i) * 8];
      float4 wb = *(const float4*)&wlds[(544 + i) * 8 + 4];
      acc[0] += wa.x * xv; acc[1] += wa.y * xv; acc[2] += wa.z * xv; acc[3] += wa.w * xv;
      acc[4] += wb.x * xv; acc[5] += wb.y * xv; acc[6] += wb.z * xv; acc[7] += wb.w * xv;
    }
    if (isZ) {
#pragma unroll
      for (int oo = 0; oo < 8; ++oo) {
        int o = o0 + oo, co = o >> 4, k = o & 15;
        out[(((size_t)b * 32 + co) * 512 + d) * 16 + k] = acc[oo] + B_w0_rpt[o] + tv[oo];
      }
    } else {
#pragma unroll
      for (int oo = 0; oo < 8; ++oo) {
        int o = o0 + oo;
        out[OUT_U0 + ((size_t)b * 32 + o) * 512 + d] = acc[oo] + B_b0[o] + tv[oo];
      }
    }
  } else if (bid < 1920) {
    // ======== zf -> zw2 ========
    int t = bid - 1280;
    int x = t & 1, rest = t >> 1;
    int oc = rest % 40, b = rest / 40;
    int o0 = oc * 8;
    for (int idx = tid; idx < 352 * 8; idx += 256) {
      int i = idx >> 3, oo = idx & 7;
      wlds[idx] = W_fin_cpt[(size_t)(o0 + oo) * 352 + i];
    }
    STAGE_RC(b);
    __syncthreads();
    {
      int g = tid >> 5, l = tid & 31;
      const float* wr = W_fin_rc + (size_t)(o0 + g) * 1344;
      float a = 0.f;
      for (int j = l; j < 1344; j += 32) a += wr[j] * rcs[j];
      a += __shfl_xor(a, 16); a += __shfl_xor(a, 8); a += __shfl_xor(a, 4);
      a += __shfl_xor(a, 2); a += __shfl_xor(a, 1);
      if (l == 0) tv[g] = a + B_fin_rc[o0 + g];
    }
    __syncthreads();
    int d = x * 256 + tid;
    float acc[8] = {0, 0, 0, 0, 0, 0, 0, 0};
    const float* xp = w2 + (size_t)b * 320 * 512 + d;
#pragma unroll 4
    for (int i = 0; i < 320; ++i) {
      float xv = xp[(size_t)i * 512];
      float4 wa = *(const float4*)&wlds[i * 8];
      float4 wb = *(const float4*)&wlds[i * 8 + 4];
      acc[0] += wa.x * xv; acc[1] += wa.y * xv; acc[2] += wa.z * xv; acc[3] += wa.w * xv;
      acc[4] += wb.x * xv; acc[5] += wb.y * xv; acc[6] += wb.z * xv; acc[7] += wb.w * xv;
    }
#pragma unroll 4
    for (int i = 0; i < 32; ++i) {
      float xv = cm1[((size_t)b * 32 + i) * 512 + d];
      float4 wa = *(const float4*)&wlds[(320 + i) * 8];
      float4 wb = *(const float4*)&wlds[(320 + i) * 8 + 4];
      acc[0] += wa.x * xv; acc[1] += wa.y * xv; acc[2] += wa.z * xv; acc[3] += wa.w * xv;
      acc[4] += wb.x * xv; acc[5] += wb.y * xv; acc[6] += wb.z * xv; acc[7] += wb.w * xv;
    }
#pragma unroll
    for (int oo = 0; oo < 8; ++oo) {
      int o = o0 + oo;
      out[OUT_ZW2 + ((size_t)b * 320 + o) * 512 + d] = acc[oo] + B_fin_cpt[o] + tv[oo];
    }
  } else {
    // ======== u2: 16-lane group per row, lane-parallel dot ========
    int b = bid - 1920;
    STAGE_RC(b);
    __syncthreads();
    int g = tid >> 4, l = tid & 15;  // 16 groups x 16 lanes
    for (int r = g; r < 320; r += 16) {
      const float* wr = W_bfin_rc + (size_t)r * 1344;
      float a = 0.f;
      for (int j = l; j < 1344; j += 16) a += wr[j] * rcs[j];
      a += __shfl_xor(a, 8); a += __shfl_xor(a, 4);
      a += __shfl_xor(a, 2); a += __shfl_xor(a, 1);
      if (l == 0) out[OUT_U2 + (size_t)b * 320 + r] = a + B_bfin_rc[r];
    }
  }
#undef STAGE_RC
}

// ---- K3: zw1 = W_l1 . w1 + rterm + cterm (float4, 2 rows/block, W_l1^T in LDS) ----
__global__ __launch_bounds__(256) void kzw1(
    const float* __restrict__ w1, const float* __restrict__ W_l1,
    const float* __restrict__ rterm, const float* __restrict__ cterm,
    float* __restrict__ out) {
  __shared__ float wl[1024];
  int hp = blockIdx.x, b = blockIdx.y;
  int t = threadIdx.x;
  for (int i = t; i < 1024; i += 256) wl[(i & 31) * 32 + (i >> 5)] = W_l1[i];
  __syncthreads();
  int h0 = hp * 2;
  int hoff = t >> 7;
  int w = (t & 127) * 4;
  float4 acc[32];
#pragma unroll
  for (int o = 0; o < 32; ++o) acc[o] = make_float4(0.f, 0.f, 0.f, 0.f);
  const float* src = w1 + ((size_t)b * 32 * 512 + h0) * 512 + 4 * t;
#pragma unroll 4
  for (int i = 0; i < 32; ++i) {
    float4 x = *(const float4*)(src + (size_t)i * 262144);
    const float* wp = wl + i * 32;
#pragma unroll
    for (int o = 0; o < 32; ++o) {
      acc[o].x += wp[o] * x.x;
      acc[o].y += wp[o] * x.y;
      acc[o].z += wp[o] * x.z;
      acc[o].w += wp[o] * x.w;
    }
  }
  int h = h0 + hoff;
#pragma unroll
  for (int o = 0; o < 32; ++o) {
    float cf = cterm[((size_t)b * 32 + o) * 512 + h];
    float4 rt = *(const float4*)(rterm + ((size_t)b * 32 + o) * 512 + w);
    float4 res = make_float4(acc[o].x + rt.x + cf, acc[o].y + rt.y + cf,
                             acc[o].z + rt.z + cf, acc[o].w + rt.w + cf);
    *(float4*)(out + (size_t)OUT_ZW1 + (((size_t)b * 32 + o) * 512 + h) * 512 + w) = res;
  }
}

extern "C" void kernel_launch(void* const* d_in, const int* in_sizes, int n_in,
                              void* d_out, int out_size, void* d_ws, size_t ws_size,
                              hipStream_t stream) {
  const float* w0 = (const float*)d_in[0];
  const float* w1 = (const float*)d_in[1];
  const float* w2 = (const float*)d_in[2];
  const float* b0 = (const float*)d_in[3];
  const float* b1 = (const float*)d_in[4];
  const float* b2 = (const float*)d_in[5];
  const float* W_w0_rpt = (const float*)d_in[6];
  const float* B_w0_rpt = (const float*)d_in[7];
  const float* W_w0_rc = (const float*)d_in[8];
  const float* B_w0_rc = (const float*)d_in[9];
  const float* W_b0 = (const float*)d_in[10];
  const float* B_b0 = (const float*)d_in[11];
  const float* W_b0_rc = (const float*)d_in[12];
  const float* B_b0_rc = (const float*)d_in[13];
  const float* W_l1 = (const float*)d_in[14];
  const float* B_l1 = (const float*)d_in[15];
  const float* W_l1_rc = (const float*)d_in[16];
  const float* B_l1_rc = (const float*)d_in[17];
  const float* W_l1_r = (const float*)d_in[18];
  const float* B_l1_r = (const float*)d_in[19];
  const float* W_l1_c = (const float*)d_in[20];
  const float* B_l1_c = (const float*)d_in[21];
  const float* W_bias1 = (const float*)d_in[22];
  const float* B_bias1 = (const float*)d_in[23];
  const float* W_bias1_rc = (const float*)d_in[24];
  const float* B_bias1_rc = (const float*)d_in[25];
  const float* W_fin_cpt = (const float*)d_in[26];
  const float* B_fin_cpt = (const float*)d_in[27];
  const float* W_fin_rc = (const float*)d_in[28];
  const float* B_fin_rc = (const float*)d_in[29];
  const float* W_bfin_rc = (const float*)d_in[30];
  const float* B_bfin_rc = (const float*)d_in[31];
  float* ws = (float*)d_ws;
  float* out = (float*)d_out;

  ksetup<<<dim3(1536), 256, 0, stream>>>(w0, w2, b0, b1, b2, w1, ws);

  kbig<<<dim3(1928), 256, 0, stream>>>(
      ws, out, b0, b1, w2, W_l1_r, B_l1_r, W_l1_c, B_l1_c, B_l1, W_bias1, B_bias1,
      W_l1_rc, B_l1_rc, W_bias1_rc, B_bias1_rc, W_w0_rpt, B_w0_rpt, W_b0, B_b0,
      W_w0_rc, B_w0_rc, W_b0_rc, B_b0_rc, W_fin_cpt, B_fin_cpt, W_fin_rc, B_fin_rc,
      W_bfin_rc, B_bfin_rc);

  kzw1<<<dim3(256, 8), 256, 0, stream>>>(w1, W_l1, ws + WS_RTERM, ws + WS_CTERM, out);
  (void)in_sizes; (void)n_in; (void)out_size; (void)ws_size;
}

// Round 8
// 360.696 us; speedup vs baseline: 2.0705x; 2.0705x over previous
//
#include <hip/hip_runtime.h>

// ---------------- constants ----------------
// B=8, C=32, CO=32, NIN=16, NOUT=10, D1=D2=512, NRC=1344
#define OUT_ZW1 2097152u
#define OUT_ZW2 69206016u
#define OUT_U0  70516736u
#define OUT_U1  70647808u
#define OUT_U2  70778880u

// workspace layout (floats) — no global atomics
#define WS_RM1P   0u        // [4][256][512] w1 col-sum partials; krcgemm combines into slot 0
#define WS_CM1    524288u
#define WS_CM0    655360u
#define WS_RM2    786432u
#define WS_RCW1   917504u   // [4][256]
#define WS_RC     918528u   // [8][1344] (entries 32..63 assembled from RCW1 at use)
#define WS_RTERM  929280u
#define WS_CTERM  1060352u
#define WS_W0T    1191424u  // [8][512][512], ends 3288576
#define WS_TW0    3288576u
#define WS_TB0    3292672u
#define WS_TL1    3292928u
#define WS_TBIAS1 3293184u
#define WS_TFIN   3293440u  // ends 3296000

static __device__ __forceinline__ float wave_reduce(float v) {
#pragma unroll
  for (int off = 32; off > 0; off >>= 1) v += __shfl_down(v, off);
  return v;
}

// ---- K1: small stats [0,256) | w1 stats [256,1280) | w0 transpose [1280,1536) ----
__global__ __launch_bounds__(256) void ksetup(
    const float* __restrict__ w0, const float* __restrict__ w2,
    const float* __restrict__ b0, const float* __restrict__ b1,
    const float* __restrict__ b2, const float* __restrict__ w1,
    float* __restrict__ ws) {
  __shared__ float sred[16];
  __shared__ float stot;
  __shared__ float rpart[512];
  __shared__ float swsum[4];
  int tid = threadIdx.x, lane = tid & 63;
  int bx = blockIdx.x;

  if (bx < 256) {
    int bc = bx;
    int b = bc >> 5, c = bc & 31;
    float* rcb = ws + WS_RC + b * 1344;
    float* cm0 = ws + WS_CM0;
    float* rm2 = ws + WS_RM2;

    if (tid < 16) sred[tid] = 0.f;
    if (tid == 0) stot = 0.f;
    __syncthreads();
    {
      float rm0p[16];
#pragma unroll
      for (int k = 0; k < 16; ++k) rm0p[k] = 0.f;
      float tot = 0.f;
      for (int d = tid; d < 512; d += 256) {
        const float4* p = (const float4*)(w0 + ((size_t)bc * 512 + d) * 16);
        float s = 0.f;
#pragma unroll
        for (int q = 0; q < 4; ++q) {
          float4 v = p[q];
          s += v.x + v.y + v.z + v.w;
          rm0p[q * 4 + 0] += v.x; rm0p[q * 4 + 1] += v.y;
          rm0p[q * 4 + 2] += v.z; rm0p[q * 4 + 3] += v.w;
        }
        cm0[(size_t)bc * 512 + d] = s * (1.f / 16.f);
        tot += s;
      }
#pragma unroll
      for (int k = 0; k < 16; ++k) {
        float r = wave_reduce(rm0p[k]);
        if (lane == 0) atomicAdd(&sred[k], r);  // LDS atomic (intra-block only)
      }
      float rt = wave_reduce(tot);
      if (lane == 0) atomicAdd(&stot, rt);
    }
    __syncthreads();
    if (tid < 16) rcb[192 + c * 16 + tid] = sred[tid] * (1.f / 512.f);
    if (tid == 0) rcb[c] = stot * (1.f / 8192.f);
    __syncthreads();

    if (tid < 10) sred[tid] = 0.f;
    if (tid == 0) stot = 0.f;
    __syncthreads();
    {
      float cm2p[10];
#pragma unroll
      for (int k = 0; k < 10; ++k) cm2p[k] = 0.f;
      float tot = 0.f;
      for (int d = tid; d < 512; d += 256) {
        float s = 0.f;
#pragma unroll
        for (int k = 0; k < 10; ++k) {
          float v = w2[((size_t)bc * 10 + k) * 512 + d];
          s += v; cm2p[k] += v;
        }
        rm2[(size_t)bc * 512 + d] = s * 0.1f;
        tot += s;
      }
#pragma unroll
      for (int k = 0; k < 10; ++k) {
        float r = wave_reduce(cm2p[k]);
        if (lane == 0) atomicAdd(&sred[k], r);
      }
      float rt = wave_reduce(tot);
      if (lane == 0) atomicAdd(&stot, rt);
    }
    __syncthreads();
    if (tid < 10) rcb[704 + c * 10 + tid] = sred[tid] * (1.f / 512.f);
    if (tid == 0) rcb[64 + c] = stot * (1.f / 5120.f);
    __syncthreads();

    if (tid < 2) sred[tid] = 0.f;
    __syncthreads();
    {
      float t0 = 0.f, t1 = 0.f;
      for (int d = tid; d < 512; d += 256) {
        t0 += b0[(size_t)bc * 512 + d];
        t1 += b1[(size_t)bc * 512 + d];
      }
      t0 = wave_reduce(t0); t1 = wave_reduce(t1);
      if (lane == 0) { atomicAdd(&sred[0], t0); atomicAdd(&sred[1], t1); }
    }
    __syncthreads();
    if (tid == 0) {
      rcb[96 + c] = sred[0] * (1.f / 512.f);
      rcb[128 + c] = sred[1] * (1.f / 512.f);
    }

    float vb2 = 0.f;
    if (tid < 10) {
      vb2 = b2[bc * 10 + tid];
      rcb[1024 + c * 10 + tid] = vb2;
    }
    if (tid < 64) {
      float s = wave_reduce(vb2);
      if (tid == 0) rcb[160 + c] = s * 0.1f;
    }
  } else if (bx < 1280) {
    int idx = bx - 256;
    int bc = idx >> 2, hc = idx & 3;
    int wid = tid >> 6;
    const float* base = w1 + (size_t)bc * 262144 + (size_t)hc * 65536;
    float col0 = 0.f, col1 = 0.f;
    for (int hl = 0; hl < 128; ++hl) {
      float2 x = *(const float2*)(base + hl * 512 + 2 * tid);
      col0 += x.x; col1 += x.y;
      float r = wave_reduce(x.x + x.y);
      if (lane == 0) rpart[hl * 4 + wid] = r;
    }
    __syncthreads();
    if (tid < 128) {
      float s = rpart[tid * 4] + rpart[tid * 4 + 1] + rpart[tid * 4 + 2] + rpart[tid * 4 + 3];
      ws[WS_CM1 + (size_t)bc * 512 + hc * 128 + tid] = s * (1.f / 512.f);
    }
    ws[WS_RM1P + (size_t)hc * 131072 + (size_t)bc * 512 + 2 * tid] = col0;
    ws[WS_RM1P + (size_t)hc * 131072 + (size_t)bc * 512 + 2 * tid + 1] = col1;
    float bt = wave_reduce(col0 + col1);
    if (lane == 0) swsum[wid] = bt;
    __syncthreads();
    if (tid == 0)
      ws[WS_RCW1 + hc * 256 + bc] = swsum[0] + swsum[1] + swsum[2] + swsum[3];
  } else {
    int bc = bx - 1280;
    int b = bc >> 5, c = bc & 31;
    for (int dd = 0; dd < 2; ++dd) {
      int d = tid + dd * 256;
      const float4* src = (const float4*)(w0 + ((size_t)bc * 512 + d) * 16);
      float4 v0 = src[0], v1 = src[1], v2 = src[2], v3 = src[3];
      float vals[16] = {v0.x, v0.y, v0.z, v0.w, v1.x, v1.y, v1.z, v1.w,
                        v2.x, v2.y, v2.z, v2.w, v3.x, v3.y, v3.z, v3.w};
#pragma unroll
      for (int k = 0; k < 16; ++k)
        ws[WS_W0T + ((size_t)(b * 512 + c * 16 + k)) * 512 + d] = vals[k];
    }
  }
}

// ---- K2: rc projections (wave/row) [0,2496) + rm1 partial combine [2496,3008) ----
__global__ __launch_bounds__(256) void krcgemm(
    float* __restrict__ ws,
    const float* __restrict__ W_w0_rc, const float* __restrict__ B_w0_rc,
    const float* __restrict__ W_b0_rc, const float* __restrict__ B_b0_rc,
    const float* __restrict__ W_l1_rc, const float* __restrict__ B_l1_rc,
    const float* __restrict__ W_bias1_rc, const float* __restrict__ B_bias1_rc,
    const float* __restrict__ W_fin_rc, const float* __restrict__ B_fin_rc,
    const float* __restrict__ W_bfin_rc, const float* __restrict__ B_bfin_rc,
    float* __restrict__ u2out) {
  int blk = blockIdx.x, tid = threadIdx.x;
  if (blk >= 2496) {
    // combine w1 col-sum partials in place (slot 0) — ksetup rewrites them every call
    int i = (blk - 2496) * 256 + tid;  // 131072 = 512*256
    ws[WS_RM1P + i] = ws[WS_RM1P + i] + ws[WS_RM1P + 131072 + i] +
                      ws[WS_RM1P + 262144 + i] + ws[WS_RM1P + 393216 + i];
    return;
  }
  int b = blk / 312;
  int lane = tid & 63, wid = tid >> 6;
  int r = (blk % 312) * 4 + wid;
  __shared__ float rcs[1344];
  for (int j = tid; j < 1344; j += 256)
    if (j < 32 || j >= 64) rcs[j] = ws[WS_RC + b * 1344 + j];
  if (tid < 32)
    rcs[32 + tid] = (ws[WS_RCW1 + 0 * 256 + b * 32 + tid] +
                     ws[WS_RCW1 + 1 * 256 + b * 32 + tid] +
                     ws[WS_RCW1 + 2 * 256 + b * 32 + tid] +
                     ws[WS_RCW1 + 3 * 256 + b * 32 + tid]) * (1.f / 262144.f);
  __syncthreads();
  const float* W; const float* Bb; float* dst; int row;
  if (r < 512)      { W = W_w0_rc;    Bb = B_w0_rc;    row = r;       dst = ws + WS_TW0 + b * 512; }
  else if (r < 544) { W = W_b0_rc;    Bb = B_b0_rc;    row = r - 512; dst = ws + WS_TB0 + b * 32; }
  else if (r < 576) { W = W_l1_rc;    Bb = B_l1_rc;    row = r - 544; dst = ws + WS_TL1 + b * 32; }
  else if (r < 608) { W = W_bias1_rc; Bb = B_bias1_rc; row = r - 576; dst = ws + WS_TBIAS1 + b * 32; }
  else if (r < 928) { W = W_fin_rc;   Bb = B_fin_rc;   row = r - 608; dst = ws + WS_TFIN + b * 320; }
  else              { W = W_bfin_rc;  Bb = B_bfin_rc;  row = r - 928; dst = u2out + b * 320; }
  const float* wr = W + (size_t)row * 1344;
  float acc = 0.f;
  for (int j = lane; j < 1344; j += 64) acc += wr[j] * rcs[j];
  acc = wave_reduce(acc);
  if (lane == 0) dst[row] = acc + Bb[row];
}

// ---- K3 (R5-proven): rcterm [0,128) | z0/u0 [128,1216) | zf [1216,1856) ----
__global__ __launch_bounds__(256) void kbig(
    const float* __restrict__ rm1, const float* __restrict__ cm0,
    const float* __restrict__ b0, const float* __restrict__ w0T,
    const float* __restrict__ W_l1_r, const float* __restrict__ B_l1_r,
    float* __restrict__ rterm,
    const float* __restrict__ cm1, const float* __restrict__ b1,
    const float* __restrict__ rm2, const float* __restrict__ w2,
    const float* __restrict__ W_l1_c, const float* __restrict__ B_l1_c,
    const float* __restrict__ B_l1, const float* __restrict__ t_l1,
    const float* __restrict__ W_bias1, const float* __restrict__ B_bias1,
    const float* __restrict__ t_bias1,
    float* __restrict__ cterm_full, float* __restrict__ u1out,
    const float* __restrict__ W_w0_rpt, const float* __restrict__ B_rpt,
    const float* __restrict__ W_b0, const float* __restrict__ B_b0w,
    const float* __restrict__ t_w0, const float* __restrict__ t_b0,
    const float* __restrict__ W_fin_cpt, const float* __restrict__ B_fin,
    const float* __restrict__ t_fin, float* __restrict__ out) {
  __shared__ float wlds[6656];  // 26 KB
  int bid = blockIdx.x, tid = threadIdx.x;

  if (bid < 128) {
    int x = bid & 1, oy = (bid >> 1) & 7, b = bid >> 4;
    int p = x * 256 + tid;
    if (oy < 4) {
      int o0 = oy * 8;
      for (int idx = tid; idx < 608 * 8; idx += 256) {
        int i = idx >> 3, oo = idx & 7;
        wlds[idx] = W_l1_r[(size_t)(o0 + oo) * 608 + i];
      }
      __syncthreads();
      float acc[8] = {0, 0, 0, 0, 0, 0, 0, 0};
#pragma unroll 4
      for (int i = 0; i < 32; ++i) {
        float xv = rm1[((size_t)b * 32 + i) * 512 + p] * (1.f / 512.f);
        float4 wa = *(const float4*)&wlds[i * 8];
        float4 wb = *(const float4*)&wlds[i * 8 + 4];
        acc[0] += wa.x * xv; acc[1] += wa.y * xv; acc[2] += wa.z * xv; acc[3] += wa.w * xv;
        acc[4] += wb.x * xv; acc[5] += wb.y * xv; acc[6] += wb.z * xv; acc[7] += wb.w * xv;
      }
#pragma unroll 4
      for (int i = 0; i < 32; ++i) {
        float xv = cm0[((size_t)b * 32 + i) * 512 + p];
        float4 wa = *(const float4*)&wlds[(32 + i) * 8];
        float4 wb = *(const float4*)&wlds[(32 + i) * 8 + 4];
        acc[0] += wa.x * xv; acc[1] += wa.y * xv; acc[2] += wa.z * xv; acc[3] += wa.w * xv;
        acc[4] += wb.x * xv; acc[5] += wb.y * xv; acc[6] += wb.z * xv; acc[7] += wb.w * xv;
      }
#pragma unroll 4
      for (int i = 0; i < 32; ++i) {
        float xv = b0[((size_t)b * 32 + i) * 512 + p];
        float4 wa = *(const float4*)&wlds[(64 + i) * 8];
        float4 wb = *(const float4*)&wlds[(64 + i) * 8 + 4];
        acc[0] += wa.x * xv; acc[1] += wa.y * xv; acc[2] += wa.z * xv; acc[3] += wa.w * xv;
        acc[4] += wb.x * xv; acc[5] += wb.y * xv; acc[6] += wb.z * xv; acc[7] += wb.w * xv;
      }
      const float* xp = w0T + (size_t)b * 512 * 512 + p;
#pragma unroll 4
      for (int i = 0; i < 512; ++i) {
        float xv = xp[(size_t)i * 512];
        float4 wa = *(const float4*)&wlds[(96 + i) * 8];
        float4 wb = *(const float4*)&wlds[(96 + i) * 8 + 4];
        acc[0] += wa.x * xv; acc[1] += wa.y * xv; acc[2] += wa.z * xv; acc[3] += wa.w * xv;
        acc[4] += wb.x * xv; acc[5] += wb.y * xv; acc[6] += wb.z * xv; acc[7] += wb.w * xv;
      }
#pragma unroll
      for (int oo = 0; oo < 8; ++oo) {
        int o = o0 + oo;
        rterm[((size_t)b * 32 + o) * 512 + p] = acc[oo] + B_l1_r[o];
      }
    } else {
      int o0 = (oy - 4) * 8;
      for (int idx = tid; idx < 416 * 8; idx += 256) {
        int i = idx >> 3, oo = idx & 7;
        wlds[idx] = W_l1_c[(size_t)(o0 + oo) * 416 + i];
        wlds[3328 + idx] = W_bias1[(size_t)(o0 + oo) * 416 + i];
      }
      __syncthreads();
      float ac[8] = {0, 0, 0, 0, 0, 0, 0, 0};
      float au[8] = {0, 0, 0, 0, 0, 0, 0, 0};
#pragma unroll 4
      for (int i = 0; i < 32; ++i) {
        float xv = cm1[((size_t)b * 32 + i) * 512 + p];
        float4 wa = *(const float4*)&wlds[i * 8];
        float4 wb = *(const float4*)&wlds[i * 8 + 4];
        float4 va = *(const float4*)&wlds[3328 + i * 8];
        float4 vb = *(const float4*)&wlds[3328 + i * 8 + 4];
        ac[0] += wa.x * xv; ac[1] += wa.y * xv; ac[2] += wa.z * xv; ac[3] += wa.w * xv;
        ac[4] += wb.x * xv; ac[5] += wb.y * xv; ac[6] += wb.z * xv; ac[7] += wb.w * xv;
        au[0] += va.x * xv; au[1] += va.y * xv; au[2] += va.z * xv; au[3] += va.w * xv;
        au[4] += vb.x * xv; au[5] += vb.y * xv; au[6] += vb.z * xv; au[7] += vb.w * xv;
      }
#pragma unroll 4
      for (int i = 0; i < 32; ++i) {
        float xv = b1[((size_t)b * 32 + i) * 512 + p];
        float4 wa = *(const float4*)&wlds[(32 + i) * 8];
        float4 wb = *(const float4*)&wlds[(32 + i) * 8 + 4];
        float4 va = *(const float4*)&wlds[3328 + (32 + i) * 8];
        float4 vb = *(const float4*)&wlds[3328 + (32 + i) * 8 + 4];
        ac[0] += wa.x * xv; ac[1] += wa.y * xv; ac[2] += wa.z * xv; ac[3] += wa.w * xv;
        ac[4] += wb.x * xv; ac[5] += wb.y * xv; ac[6] += wb.z * xv; ac[7] += wb.w * xv;
        au[0] += va.x * xv; au[1] += va.y * xv; au[2] += va.z * xv; au[3] += va.w * xv;
        au[4] += vb.x * xv; au[5] += vb.y * xv; au[6] += vb.z * xv; au[7] += vb.w * xv;
      }
#pragma unroll 4
      for (int i = 0; i < 32; ++i) {
        float xv = rm2[((size_t)b * 32 + i) * 512 + p];
        float4 wa = *(const float4*)&wlds[(64 + i) * 8];
        float4 wb = *(const float4*)&wlds[(64 + i) * 8 + 4];
        float4 va = *(const float4*)&wlds[3328 + (64 + i) * 8];
        float4 vb = *(const float4*)&wlds[3328 + (64 + i) * 8 + 4];
        ac[0] += wa.x * xv; ac[1] += wa.y * xv; ac[2] += wa.z * xv; ac[3] += wa.w * xv;
        ac[4] += wb.x * xv; ac[5] += wb.y * xv; ac[6] += wb.z * xv; ac[7] += wb.w * xv;
        au[0] += va.x * xv; au[1] += va.y * xv; au[2] += va.z * xv; au[3] += va.w * xv;
        au[4] += vb.x * xv; au[5] += vb.y * xv; au[6] += vb.z * xv; au[7] += vb.w * xv;
      }
      const float* xp = w2 + (size_t)b * 320 * 512 + p;
#pragma unroll 4
      for (int i = 0; i < 320; ++i) {
        float xv = xp[(size_t)i * 512];
        float4 wa = *(const float4*)&wlds[(96 + i) * 8];
        float4 wb = *(const float4*)&wlds[(96 + i) * 8 + 4];
        float4 va = *(const float4*)&wlds[3328 + (96 + i) * 8];
        float4 vb = *(const float4*)&wlds[3328 + (96 + i) * 8 + 4];
        ac[0] += wa.x * xv; ac[1] += wa.y * xv; ac[2] += wa.z * xv; ac[3] += wa.w * xv;
        ac[4] += wb.x * xv; ac[5] += wb.y * xv; ac[6] += wb.z * xv; ac[7] += wb.w * xv;
        au[0] += va.x * xv; au[1] += va.y * xv; au[2] += va.z * xv; au[3] += va.w * xv;
        au[4] += vb.x * xv; au[5] += vb.y * xv; au[6] += vb.z * xv; au[7] += vb.w * xv;
      }
#pragma unroll
      for (int oo = 0; oo < 8; ++oo) {
        int o = o0 + oo;
        cterm_full[((size_t)b * 32 + o) * 512 + p] = ac[oo] + B_l1_c[o] + B_l1[o] + t_l1[b * 32 + o];
        u1out[((size_t)b * 32 + o) * 512 + p] = au[oo] + B_bias1[o] + t_bias1[b * 32 + o];
      }
    }
  } else if (bid < 1216) {
    int t = bid - 128;
    int x = t & 1, rest = t >> 1;
    int oc = rest % 68, b = rest / 68;
    bool isZ = oc < 64;
    int o0 = isZ ? oc * 8 : (oc - 64) * 8;
    const float* Wsrc = isZ ? W_w0_rpt : W_b0;
    for (int idx = tid; idx < 576 * 8; idx += 256) {
      int i = idx >> 3, oo = idx & 7;
      wlds[idx] = Wsrc[(size_t)(o0 + oo) * 576 + i];
    }
    __syncthreads();
    int d = x * 256 + tid;
    float acc[8] = {0, 0, 0, 0, 0, 0, 0, 0};
    const float* xp = w0T + (size_t)b * 512 * 512 + d;
#pragma unroll 4
    for (int i = 0; i < 512; ++i) {
      float xv = xp[(size_t)i * 512];
      float4 wa = *(const float4*)&wlds[i * 8];
      float4 wb = *(const float4*)&wlds[i * 8 + 4];
      acc[0] += wa.x * xv; acc[1] += wa.y * xv; acc[2] += wa.z * xv; acc[3] += wa.w * xv;
      acc[4] += wb.x * xv; acc[5] += wb.y * xv; acc[6] += wb.z * xv; acc[7] += wb.w * xv;
    }
#pragma unroll 4
    for (int i = 0; i < 32; ++i) {
      float xv = rm1[((size_t)b * 32 + i) * 512 + d] * (1.f / 512.f);
      float4 wa = *(const float4*)&wlds[(512 + i) * 8];
      float4 wb = *(const float4*)&wlds[(512 + i) * 8 + 4];
      acc[0] += wa.x * xv; acc[1] += wa.y * xv; acc[2] += wa.z * xv; acc[3] += wa.w * xv;
      acc[4] += wb.x * xv; acc[5] += wb.y * xv; acc[6] += wb.z * xv; acc[7] += wb.w * xv;
    }
#pragma unroll 4
    for (int i = 0; i < 32; ++i) {
      float xv = b0[((size_t)b * 32 + i) * 512 + d];
      float4 wa = *(const float4*)&wlds[(544 + i) * 8];
      float4 wb = *(const float4*)&wlds[(544 + i) * 8 + 4];
      acc[0] += wa.x * xv; acc[1] += wa.y * xv; acc[2] += wa.z * xv; acc[3] += wa.w * xv;
      acc[4] += wb.x * xv; acc[5] += wb.y * xv; acc[6] += wb.z * xv; acc[7] += wb.w * xv;
    }
    if (isZ) {
#pragma unroll
      for (int oo = 0; oo < 8; ++oo) {
        int o = o0 + oo, co = o >> 4, k = o & 15;
        out[(((size_t)b * 32 + co) * 512 + d) * 16 + k] = acc[oo] + B_rpt[o] + t_w0[b * 512 + o];
      }
    } else {
#pragma unroll
      for (int oo = 0; oo < 8; ++oo) {
        int o = o0 + oo;
        out[OUT_U0 + ((size_t)b * 32 + o) * 512 + d] = acc[oo] + B_b0w[o] + t_b0[b * 32 + o];
      }
    }
  } else {
    int t = bid - 1216;
    int x = t & 1, rest = t >> 1;
    int oc = rest % 40, b = rest / 40;
    int o0 = oc * 8;
    for (int idx = tid; idx < 352 * 8; idx += 256) {
      int i = idx >> 3, oo = idx & 7;
      wlds[idx] = W_fin_cpt[(size_t)(o0 + oo) * 352 + i];
    }
    __syncthreads();
    int d = x * 256 + tid;
    float acc[8] = {0, 0, 0, 0, 0, 0, 0, 0};
    const float* xp = w2 + (size_t)b * 320 * 512 + d;
#pragma unroll 4
    for (int i = 0; i < 320; ++i) {
      float xv = xp[(size_t)i * 512];
      float4 wa = *(const float4*)&wlds[i * 8];
      float4 wb = *(const float4*)&wlds[i * 8 + 4];
      acc[0] += wa.x * xv; acc[1] += wa.y * xv; acc[2] += wa.z * xv; acc[3] += wa.w * xv;
      acc[4] += wb.x * xv; acc[5] += wb.y * xv; acc[6] += wb.z * xv; acc[7] += wb.w * xv;
    }
#pragma unroll 4
    for (int i = 0; i < 32; ++i) {
      float xv = cm1[((size_t)b * 32 + i) * 512 + d];
      float4 wa = *(const float4*)&wlds[(320 + i) * 8];
      float4 wb = *(const float4*)&wlds[(320 + i) * 8 + 4];
      acc[0] += wa.x * xv; acc[1] += wa.y * xv; acc[2] += wa.z * xv; acc[3] += wa.w * xv;
      acc[4] += wb.x * xv; acc[5] += wb.y * xv; acc[6] += wb.z * xv; acc[7] += wb.w * xv;
    }
#pragma unroll
    for (int oo = 0; oo < 8; ++oo) {
      int o = o0 + oo;
      out[OUT_ZW2 + ((size_t)b * 320 + o) * 512 + d] = acc[oo] + B_fin[o] + t_fin[b * 320 + o];
    }
  }
}

// ---- K4: zw1 = W_l1 . w1 + rterm + cterm (float4, 2 rows/block, W_l1^T in LDS) ----
__global__ __launch_bounds__(256) void kzw1(
    const float* __restrict__ w1, const float* __restrict__ W_l1,
    const float* __restrict__ rterm, const float* __restrict__ cterm,
    float* __restrict__ out) {
  __shared__ float wl[1024];
  int hp = blockIdx.x, b = blockIdx.y;
  int t = threadIdx.x;
  for (int i = t; i < 1024; i += 256) wl[(i & 31) * 32 + (i >> 5)] = W_l1[i];
  __syncthreads();
  int h0 = hp * 2;
  int hoff = t >> 7;
  int w = (t & 127) * 4;
  float4 acc[32];
#pragma unroll
  for (int o = 0; o < 32; ++o) acc[o] = make_float4(0.f, 0.f, 0.f, 0.f);
  const float* src = w1 + ((size_t)b * 32 * 512 + h0) * 512 + 4 * t;
#pragma unroll 4
  for (int i = 0; i < 32; ++i) {
    float4 x = *(const float4*)(src + (size_t)i * 262144);
    const float* wp = wl + i * 32;
#pragma unroll
    for (int o = 0; o < 32; ++o) {
      acc[o].x += wp[o] * x.x;
      acc[o].y += wp[o] * x.y;
      acc[o].z += wp[o] * x.z;
      acc[o].w += wp[o] * x.w;
    }
  }
  int h = h0 + hoff;
#pragma unroll
  for (int o = 0; o < 32; ++o) {
    float cf = cterm[((size_t)b * 32 + o) * 512 + h];
    float4 rt = *(const float4*)(rterm + ((size_t)b * 32 + o) * 512 + w);
    float4 res = make_float4(acc[o].x + rt.x + cf, acc[o].y + rt.y + cf,
                             acc[o].z + rt.z + cf, acc[o].w + rt.w + cf);
    *(float4*)(out + (size_t)OUT_ZW1 + (((size_t)b * 32 + o) * 512 + h) * 512 + w) = res;
  }
}

extern "C" void kernel_launch(void* const* d_in, const int* in_sizes, int n_in,
                              void* d_out, int out_size, void* d_ws, size_t ws_size,
                              hipStream_t stream) {
  const float* w0 = (const float*)d_in[0];
  const float* w1 = (const float*)d_in[1];
  const float* w2 = (const float*)d_in[2];
  const float* b0 = (const float*)d_in[3];
  const float* b1 = (const float*)d_in[4];
  const float* b2 = (const float*)d_in[5];
  const float* W_w0_rpt = (const float*)d_in[6];
  const float* B_w0_rpt = (const float*)d_in[7];
  const float* W_w0_rc = (const float*)d_in[8];
  const float* B_w0_rc = (const float*)d_in[9];
  const float* W_b0 = (const float*)d_in[10];
  const float* B_b0 = (const float*)d_in[11];
  const float* W_b0_rc = (const float*)d_in[12];
  const float* B_b0_rc = (const float*)d_in[13];
  const float* W_l1 = (const float*)d_in[14];
  const float* B_l1 = (const float*)d_in[15];
  const float* W_l1_rc = (const float*)d_in[16];
  const float* B_l1_rc = (const float*)d_in[17];
  const float* W_l1_r = (const float*)d_in[18];
  const float* B_l1_r = (const float*)d_in[19];
  const float* W_l1_c = (const float*)d_in[20];
  const float* B_l1_c = (const float*)d_in[21];
  const float* W_bias1 = (const float*)d_in[22];
  const float* B_bias1 = (const float*)d_in[23];
  const float* W_bias1_rc = (const float*)d_in[24];
  const float* B_bias1_rc = (const float*)d_in[25];
  const float* W_fin_cpt = (const float*)d_in[26];
  const float* B_fin_cpt = (const float*)d_in[27];
  const float* W_fin_rc = (const float*)d_in[28];
  const float* B_fin_rc = (const float*)d_in[29];
  const float* W_bfin_rc = (const float*)d_in[30];
  const float* B_bfin_rc = (const float*)d_in[31];
  float* ws = (float*)d_ws;
  float* out = (float*)d_out;

  ksetup<<<dim3(1536), 256, 0, stream>>>(w0, w2, b0, b1, b2, w1, ws);

  krcgemm<<<dim3(3008), 256, 0, stream>>>(
      ws, W_w0_rc, B_w0_rc, W_b0_rc, B_b0_rc, W_l1_rc, B_l1_rc, W_bias1_rc,
      B_bias1_rc, W_fin_rc, B_fin_rc, W_bfin_rc, B_bfin_rc, out + OUT_U2);

  kbig<<<dim3(1856), 256, 0, stream>>>(
      ws + WS_RM1P, ws + WS_CM0, b0, ws + WS_W0T, W_l1_r, B_l1_r, ws + WS_RTERM,
      ws + WS_CM1, b1, ws + WS_RM2, w2, W_l1_c, B_l1_c, B_l1, ws + WS_TL1, W_bias1,
      B_bias1, ws + WS_TBIAS1, ws + WS_CTERM, out + OUT_U1,
      W_w0_rpt, B_w0_rpt, W_b0, B_b0, ws + WS_TW0, ws + WS_TB0,
      W_fin_cpt, B_fin_cpt, ws + WS_TFIN, out);

  kzw1<<<dim3(256, 8), 256, 0, stream>>>(w1, W_l1, ws + WS_RTERM, ws + WS_CTERM, out);
  (void)in_sizes; (void)n_in; (void)out_size; (void)ws_size;
}